// Round 1
// baseline (1206.529 us; speedup 1.0000x reference)
//
#include <hip/hip_runtime.h>
#include <cfloat>
#include <cmath>

// Adaptive log-softmax w/ loss, forward NLL. N=2048 rows.
// Strategy (R1 baseline): all-fp32 tiled GEMMs with fused online-LSE partials
// (never materialize logits), then a per-row finalize kernel.
//   85 GFLOP fp32 -> VALU-bound; target ~1 ms this round. MFMA comes later.

#define N_ROWS 2048
#define K_IN   1024
#define HEAD_O 4002
#define CUT0   4000
#define CUT1   20000
#define T0_O   16000
#define T1_O   30257
#define H0     512
#define H1     256

// ---------------------------------------------------------------------------
// gemm128: C = X[M,K] @ W[O,K]^T over a 128x128 tile, fused row-wise online
// softmax partials (max, sumexp) per (row, col-tile) written to Pm/Ps.
// 256 threads, 8x8 microtile (split as 2x 4-col groups 64 apart to keep
// ds_read_b128 at 2-way bank aliasing = free).
// ---------------------------------------------------------------------------
__global__ __launch_bounds__(256)
void gemm128_lse(const float* __restrict__ X, const float* __restrict__ W,
                 int K, int O, int T,
                 float* __restrict__ Pm, float* __restrict__ Ps)
{
    __shared__ float Xs[16][136];   // [k][row], stride 136 floats (16B aligned)
    __shared__ float Wt[16][136];   // [k][col]

    const int bx = blockIdx.x, by = blockIdx.y;
    const int t  = threadIdx.x;
    const int tx = t & 15, ty = t >> 4;
    const int row0 = by * 128, col0 = bx * 128;

    float acc[8][8];
#pragma unroll
    for (int i = 0; i < 8; ++i)
#pragma unroll
        for (int j = 0; j < 8; ++j) acc[i][j] = 0.f;

    const int lr = t >> 1;        // 0..127
    const int lk = (t & 1) * 8;   // 0 or 8
    const float* Xp = X + (size_t)(row0 + lr) * K + lk;
    int wr = col0 + lr; if (wr > O - 1) wr = O - 1;   // clamp tail tile (masked in epilogue)
    const float* Wp = W + (size_t)wr * K + lk;

    for (int k0 = 0; k0 < K; k0 += 16) {
        const float4 x0 = *(const float4*)(Xp + k0);
        const float4 x1 = *(const float4*)(Xp + k0 + 4);
        const float4 w0 = *(const float4*)(Wp + k0);
        const float4 w1 = *(const float4*)(Wp + k0 + 4);
        __syncthreads();   // prior tile's reads done before overwrite
        Xs[lk+0][lr] = x0.x; Xs[lk+1][lr] = x0.y; Xs[lk+2][lr] = x0.z; Xs[lk+3][lr] = x0.w;
        Xs[lk+4][lr] = x1.x; Xs[lk+5][lr] = x1.y; Xs[lk+6][lr] = x1.z; Xs[lk+7][lr] = x1.w;
        Wt[lk+0][lr] = w0.x; Wt[lk+1][lr] = w0.y; Wt[lk+2][lr] = w0.z; Wt[lk+3][lr] = w0.w;
        Wt[lk+4][lr] = w1.x; Wt[lk+5][lr] = w1.y; Wt[lk+6][lr] = w1.z; Wt[lk+7][lr] = w1.w;
        __syncthreads();
#pragma unroll
        for (int kk = 0; kk < 16; ++kk) {
            const float4 a0 = *(const float4*)&Xs[kk][ty * 4];
            const float4 a1 = *(const float4*)&Xs[kk][64 + ty * 4];
            const float4 b0 = *(const float4*)&Wt[kk][tx * 4];
            const float4 b1 = *(const float4*)&Wt[kk][64 + tx * 4];
            const float av[8] = {a0.x, a0.y, a0.z, a0.w, a1.x, a1.y, a1.z, a1.w};
            const float bv[8] = {b0.x, b0.y, b0.z, b0.w, b1.x, b1.y, b1.z, b1.w};
#pragma unroll
            for (int i = 0; i < 8; ++i)
#pragma unroll
                for (int j = 0; j < 8; ++j)
                    acc[i][j] = fmaf(av[i], bv[j], acc[i][j]);
        }
    }

    // Epilogue: per-row (max, sumexp) within this col-tile; reduce across the
    // 16 tx-lanes sharing a row group (lanes are consecutive within a wave).
#pragma unroll
    for (int i = 0; i < 8; ++i) {
        float m = -FLT_MAX, s = 0.f;
#pragma unroll
        for (int j = 0; j < 8; ++j) {
            const int c = col0 + ((j >> 2) << 6) + tx * 4 + (j & 3);
            if (c < O) m = fmaxf(m, acc[i][j]);
        }
#pragma unroll
        for (int j = 0; j < 8; ++j) {
            const int c = col0 + ((j >> 2) << 6) + tx * 4 + (j & 3);
            if (c < O) s += __expf(acc[i][j] - m);
        }
#pragma unroll
        for (int off = 1; off < 16; off <<= 1) {
            const float mo = __shfl_xor(m, off);
            const float so = __shfl_xor(s, off);
            const float M2 = fmaxf(m, mo);
            // -FLT_MAX is finite: (-FLT_MAX) - (-FLT_MAX) = 0 -> no NaN path
            s = s * __expf(m - M2) + so * __expf(mo - M2);
            m = M2;
        }
        if (tx == 0) {
            const int r = row0 + ((i >> 2) << 6) + ty * 4 + (i & 3);
            Pm[(size_t)r * T + bx] = m;
            Ps[(size_t)r * T + bx] = s;
        }
    }
}

// ---------------------------------------------------------------------------
// gemm64: C = X[M,K] @ W[O,K]^T stored to C. 64x64 tile, 4x4 microtile.
// Used for the two small hidden projections (O = 512 / 256, both %64==0).
// ---------------------------------------------------------------------------
__global__ __launch_bounds__(256)
void gemm64_store(const float* __restrict__ X, const float* __restrict__ W,
                  int K, int O, float* __restrict__ C)
{
    __shared__ float Xs[16][68];
    __shared__ float Wt[16][68];
    const int t = threadIdx.x, tx = t & 15, ty = t >> 4;
    const int row0 = blockIdx.y * 64, col0 = blockIdx.x * 64;

    float acc[4][4] = {};
    const int lr = t >> 2;        // 0..63
    const int lk = (t & 3) * 4;   // 0,4,8,12
    const float* Xp = X + (size_t)(row0 + lr) * K + lk;
    const float* Wp = W + (size_t)(col0 + lr) * K + lk;

    for (int k0 = 0; k0 < K; k0 += 16) {
        const float4 xv = *(const float4*)(Xp + k0);
        const float4 wv = *(const float4*)(Wp + k0);
        __syncthreads();
        Xs[lk+0][lr] = xv.x; Xs[lk+1][lr] = xv.y; Xs[lk+2][lr] = xv.z; Xs[lk+3][lr] = xv.w;
        Wt[lk+0][lr] = wv.x; Wt[lk+1][lr] = wv.y; Wt[lk+2][lr] = wv.z; Wt[lk+3][lr] = wv.w;
        __syncthreads();
#pragma unroll
        for (int kk = 0; kk < 16; ++kk) {
            const float4 a = *(const float4*)&Xs[kk][ty * 4];
            const float4 b = *(const float4*)&Wt[kk][tx * 4];
            const float av[4] = {a.x, a.y, a.z, a.w};
            const float bv[4] = {b.x, b.y, b.z, b.w};
#pragma unroll
            for (int i = 0; i < 4; ++i)
#pragma unroll
                for (int j = 0; j < 4; ++j)
                    acc[i][j] = fmaf(av[i], bv[j], acc[i][j]);
        }
    }
#pragma unroll
    for (int i = 0; i < 4; ++i) {
        const float4 v = make_float4(acc[i][0], acc[i][1], acc[i][2], acc[i][3]);
        *(float4*)(C + (size_t)(row0 + ty * 4 + i) * O + col0 + tx * 4) = v;
    }
}

// ---------------------------------------------------------------------------
// finalize: per row, combine LSE partials + recompute the 3 gathered target
// logits as short dot products, assemble the NLL.
// ---------------------------------------------------------------------------
__device__ inline float block_sum(float v, float* sm)
{
#pragma unroll
    for (int off = 32; off > 0; off >>= 1) v += __shfl_xor(v, off);
    __syncthreads();
    if ((threadIdx.x & 63) == 0) sm[threadIdx.x >> 6] = v;
    __syncthreads();
    return sm[0] + sm[1] + sm[2] + sm[3];
}

__device__ inline void block_lse(float& m, float& s, float* smm, float* sms)
{
#pragma unroll
    for (int off = 32; off > 0; off >>= 1) {
        const float mo = __shfl_xor(m, off);
        const float so = __shfl_xor(s, off);
        const float M2 = fmaxf(m, mo);
        s = s * __expf(m - M2) + so * __expf(mo - M2);
        m = M2;
    }
    __syncthreads();
    if ((threadIdx.x & 63) == 0) { smm[threadIdx.x >> 6] = m; sms[threadIdx.x >> 6] = s; }
    __syncthreads();
    const float M2 = fmaxf(fmaxf(smm[0], smm[1]), fmaxf(smm[2], smm[3]));
    const float S  = sms[0] * __expf(smm[0] - M2) + sms[1] * __expf(smm[1] - M2)
                   + sms[2] * __expf(smm[2] - M2) + sms[3] * __expf(smm[3] - M2);
    m = M2; s = S;
}

__device__ inline void local_lse(const float* __restrict__ Pm,
                                 const float* __restrict__ Ps,
                                 int T, float& m, float& s)
{
    m = -FLT_MAX; s = 0.f;
    for (int i = threadIdx.x; i < T; i += 256) {
        const float mi = Pm[i], si = Ps[i];
        const float M2 = fmaxf(m, mi);
        s = s * __expf(m - M2) + si * __expf(mi - M2);
        m = M2;
    }
}

__global__ __launch_bounds__(256)
void finalize(const float* __restrict__ inp, const int* __restrict__ tgt,
              const float* __restrict__ head_w,
              const float* __restrict__ t0_w2, const float* __restrict__ t1_w2,
              const float* __restrict__ t0h, const float* __restrict__ t1h,
              const float* __restrict__ hPm, const float* __restrict__ hPs, int hT,
              const float* __restrict__ p0m, const float* __restrict__ p0s, int T0,
              const float* __restrict__ p1m, const float* __restrict__ p1s, int T1,
              float* __restrict__ out)
{
    __shared__ float sm[4], ss[4];
    const int row = blockIdx.x, t = threadIdx.x;
    const int tg = tgt[row];
    const bool in1 = (tg >= CUT0) && (tg < CUT1);
    const bool in2 = (tg >= CUT1);
    const int g = (tg < CUT0) ? tg : (in1 ? CUT0 : CUT0 + 1);

    // head target logit: dot(inp[row], head_w[g]), K=1024 -> 1 float4/thread
    float d;
    {
        const float4 a = *(const float4*)(inp + (size_t)row * K_IN + t * 4);
        const float4 b = *(const float4*)(head_w + (size_t)g * K_IN + t * 4);
        d = a.x * b.x + a.y * b.y + a.z * b.z + a.w * b.w;
    }
    const float dot_h = block_sum(d, sm);

    // tail0 target logit: dot(t0h[row], t0_w2[rel0]), 512
    int r0 = tg - CUT0; r0 = r0 < 0 ? 0 : (r0 > T0_O - 1 ? T0_O - 1 : r0);
    d = 0.f;
    if (t < 128) {
        const float4 a = *(const float4*)(t0h + (size_t)row * H0 + t * 4);
        const float4 b = *(const float4*)(t0_w2 + (size_t)r0 * H0 + t * 4);
        d = a.x * b.x + a.y * b.y + a.z * b.z + a.w * b.w;
    }
    const float dot0 = block_sum(d, sm);

    // tail1 target logit: dot(t1h[row], t1_w2[rel1]), 256
    int r1 = tg - CUT1; r1 = r1 < 0 ? 0 : (r1 > T1_O - 1 ? T1_O - 1 : r1);
    d = 0.f;
    if (t < 64) {
        const float4 a = *(const float4*)(t1h + (size_t)row * H1 + t * 4);
        const float4 b = *(const float4*)(t1_w2 + (size_t)r1 * H1 + t * 4);
        d = a.x * b.x + a.y * b.y + a.z * b.z + a.w * b.w;
    }
    const float dot1 = block_sum(d, sm);

    float m, s;
    local_lse(hPm + (size_t)row * hT, hPs + (size_t)row * hT, hT, m, s);
    block_lse(m, s, sm, ss);
    const float lse_h = m + logf(s);

    local_lse(p0m + (size_t)row * T0, p0s + (size_t)row * T0, T0, m, s);
    block_lse(m, s, sm, ss);
    const float lse_0 = m + logf(s);

    local_lse(p1m + (size_t)row * T1, p1s + (size_t)row * T1, T1, m, s);
    block_lse(m, s, sm, ss);
    const float lse_1 = m + logf(s);

    if (t == 0) {
        float res = dot_h - lse_h;
        if (in1) res += dot0 - lse_0;
        if (in2) res += dot1 - lse_1;
        out[row] = -res;
    }
}

// ---------------------------------------------------------------------------
extern "C" void kernel_launch(void* const* d_in, const int* in_sizes, int n_in,
                              void* d_out, int out_size, void* d_ws, size_t ws_size,
                              hipStream_t stream)
{
    const float* inp    = (const float*)d_in[0];
    const int*   tgt    = (const int*)  d_in[1];
    const float* head_w = (const float*)d_in[2];
    const float* t0_w1  = (const float*)d_in[3];
    const float* t0_w2  = (const float*)d_in[4];
    const float* t1_w1  = (const float*)d_in[5];
    const float* t1_w2  = (const float*)d_in[6];
    float* out = (float*)d_out;
    float* ws  = (float*)d_ws;

    const int hT  = (HEAD_O + 127) / 128;   // 32
    const int T0t = (T0_O  + 127) / 128;    // 125
    const int T1t = (T1_O  + 127) / 128;    // 237

    float* t0h = ws;                               // 2048*512
    float* t1h = t0h + (size_t)N_ROWS * H0;        // 2048*256
    float* hPm = t1h + (size_t)N_ROWS * H1;
    float* hPs = hPm + (size_t)N_ROWS * hT;
    float* p0m = hPs + (size_t)N_ROWS * hT;
    float* p0s = p0m + (size_t)N_ROWS * T0t;
    float* p1m = p0s + (size_t)N_ROWS * T0t;
    float* p1s = p1m + (size_t)N_ROWS * T1t;
    // total ws use: ~19.2 MB

    const dim3 blk(256);
    // hidden projections (needed before their LSE GEMMs; stream-ordered)
    gemm64_store<<<dim3(H0 / 64, N_ROWS / 64), blk, 0, stream>>>(inp, t0_w1, K_IN, H0, t0h);
    gemm64_store<<<dim3(H1 / 64, N_ROWS / 64), blk, 0, stream>>>(inp, t1_w1, K_IN, H1, t1h);
    // fused GEMM + online-LSE partials
    gemm128_lse<<<dim3(hT,  N_ROWS / 128), blk, 0, stream>>>(inp, head_w, K_IN, HEAD_O, hT,  hPm, hPs);
    gemm128_lse<<<dim3(T0t, N_ROWS / 128), blk, 0, stream>>>(t0h, t0_w2, H0,  T0_O,  T0t, p0m, p0s);
    gemm128_lse<<<dim3(T1t, N_ROWS / 128), blk, 0, stream>>>(t1h, t1_w2, H1,  T1_O,  T1t, p1m, p1s);
    // per-row assembly
    finalize<<<dim3(N_ROWS), blk, 0, stream>>>(inp, tgt, head_w, t0_w2, t1_w2, t0h, t1h,
                                               hPm, hPs, hT, p0m, p0s, T0t, p1m, p1s, T1t, out);
}

// Round 2
// 573.709 us; speedup vs baseline: 2.1030x; 2.1030x over previous
//
#include <hip/hip_runtime.h>
#include <cfloat>
#include <cmath>

// Adaptive log-softmax w/ loss, forward NLL. N=2048 rows.
// R2: big GEMMs moved to bf16 MFMA with split-precision (hi+lo) 3-term
// emulation of fp32: a*b ~= ah*bh + ah*bl + al*bh  (al*bl dropped, ~2^-18).
// LSE fused into the GEMM epilogue (never materialize logits).
// Projections (3 GF) stay fp32-VALU. Requires ws >= ~108 MB.

#define N_ROWS 2048
#define K_IN   1024
#define HEAD_O 4002
#define CUT0   4000
#define CUT1   20000
#define T0_O   16000
#define T1_O   30257
#define H0     512
#define H1     256

typedef __attribute__((ext_vector_type(8))) __bf16 bf16x8;
typedef __attribute__((ext_vector_type(4))) float f32x4;

// ---------------------------------------------------------------------------
// fp32 -> (hi, lo) bf16 planes, RNE. lo = rne(x - hi).
// ---------------------------------------------------------------------------
__device__ inline unsigned short f2bf_rne(float f) {
    unsigned u = __builtin_bit_cast(unsigned, f);
    u += 0x7FFFu + ((u >> 16) & 1u);
    return (unsigned short)(u >> 16);
}
__device__ inline float bf2f(unsigned short b) {
    return __builtin_bit_cast(float, (unsigned)b << 16);
}

__global__ __launch_bounds__(256)
void split_bf16(const float* __restrict__ x, unsigned short* __restrict__ h,
                unsigned short* __restrict__ l, int n4)
{
    for (int i = blockIdx.x * 256 + threadIdx.x; i < n4; i += gridDim.x * 256) {
        const float4 v = ((const float4*)x)[i];
        ushort4 hv, lv;
        hv.x = f2bf_rne(v.x); lv.x = f2bf_rne(v.x - bf2f(hv.x));
        hv.y = f2bf_rne(v.y); lv.y = f2bf_rne(v.y - bf2f(hv.y));
        hv.z = f2bf_rne(v.z); lv.z = f2bf_rne(v.z - bf2f(hv.z));
        hv.w = f2bf_rne(v.w); lv.w = f2bf_rne(v.w - bf2f(hv.w));
        ((ushort4*)h)[i] = hv; ((ushort4*)l)[i] = lv;
    }
}

// ---------------------------------------------------------------------------
// async global->LDS, 16 B per lane. LDS dest is wave-uniform base + lane*16.
// ---------------------------------------------------------------------------
__device__ inline void gload_lds16(const unsigned short* g, unsigned short* l) {
    __builtin_amdgcn_global_load_lds(
        (const __attribute__((address_space(1))) void*)g,
        (__attribute__((address_space(3))) void*)l, 16, 0, 0);
}

// ---------------------------------------------------------------------------
// lse_mfma: D = X[M,K] @ W[O,K]^T on a 128x128 tile via mfma_f32_16x16x32_bf16,
// 3-term split precision, fused per-row online-LSE partials per col-tile.
// 256 thr = 4 waves, each wave one 64x64 quadrant (4x4 fragments).
// LDS 32KB: Ah | Al | Bh | Bl, each [128 rows][32 k] bf16, k-group slots
// XOR-swizzled (slot = kg ^ ((row>>1)&3)) via pre-swizzled GLOBAL source
// addresses (global_load_lds writes linearly).
// ---------------------------------------------------------------------------
__global__ __launch_bounds__(256)
void lse_mfma(const unsigned short* __restrict__ Ah, const unsigned short* __restrict__ Al,
              const unsigned short* __restrict__ Bh, const unsigned short* __restrict__ Bl,
              int K, int O, int T,
              float* __restrict__ Pm, float* __restrict__ Ps)
{
    __shared__ unsigned short lds[16384];   // 32 KB
    const int t = threadIdx.x;
    const int lane = t & 63, w = t >> 6;
    const int row0 = blockIdx.y * 128, col0 = blockIdx.x * 128;
    const int kg = lane >> 4, li = lane & 15;
    const int wr = w >> 1, wc = w & 1;

    // --- staging plan: 8 issues/wave. Issue (plane p, j2): rows j*16..j*16+15
    // of plane p, j = 2*w + j2. Each lane loads 16B at (row, slot) where the
    // slot's DATA k-group is kd = slot ^ ((row>>1)&3)  (inverse==forward XOR).
    const unsigned short* gsrc[8];
    unsigned short* ldst[8];
    {
        const int slot = lane & 3;
        #pragma unroll
        for (int p = 0; p < 4; ++p) {
            #pragma unroll
            for (int j2 = 0; j2 < 2; ++j2) {
                const int j = 2 * w + j2;
                const int rl = j * 16 + (lane >> 2);
                const int kd = (slot ^ ((rl >> 1) & 3)) * 8;   // elems
                const unsigned short* base;
                int grow;
                if (p < 2) { grow = row0 + rl; base = (p == 0) ? Ah : Al; }
                else       { grow = col0 + rl; if (grow > O - 1) grow = O - 1;
                             base = (p == 2) ? Bh : Bl; }
                gsrc[p * 2 + j2] = base + (size_t)grow * K + kd;
                ldst[p * 2 + j2] = lds + p * 4096 + j * 512;   // wave-uniform
            }
        }
    }

    // --- fragment read byte-offsets (constant across K-steps)
    int aoff[4], boff[4];
    #pragma unroll
    for (int m = 0; m < 4; ++m) {
        const int ar = wr * 64 + m * 16 + li;
        aoff[m] = ar * 64 + (kg ^ ((ar >> 1) & 3)) * 16;            // into Ah
        const int bc = wc * 64 + m * 16 + li;
        boff[m] = 16384 + bc * 64 + (kg ^ ((bc >> 1) & 3)) * 16;    // into Bh
    }

    f32x4 acc[4][4];
    #pragma unroll
    for (int m = 0; m < 4; ++m)
        #pragma unroll
        for (int n = 0; n < 4; ++n) acc[m][n] = (f32x4){0.f, 0.f, 0.f, 0.f};

    const char* ldsc = (const char*)lds;
    for (int k0 = 0; k0 < K; k0 += 32) {
        #pragma unroll
        for (int i = 0; i < 8; ++i) gload_lds16(gsrc[i] + k0, ldst[i]);
        __syncthreads();                      // drains vmcnt, tile ready
        bf16x8 fah[4], fal[4], fbh[4], fbl[4];
        #pragma unroll
        for (int m = 0; m < 4; ++m) {
            fah[m] = *(const bf16x8*)(ldsc + aoff[m]);
            fal[m] = *(const bf16x8*)(ldsc + aoff[m] + 8192);
            fbh[m] = *(const bf16x8*)(ldsc + boff[m]);
            fbl[m] = *(const bf16x8*)(ldsc + boff[m] + 8192);
        }
        #pragma unroll
        for (int m = 0; m < 4; ++m)
            #pragma unroll
            for (int n = 0; n < 4; ++n) {
                acc[m][n] = __builtin_amdgcn_mfma_f32_16x16x32_bf16(fah[m], fbh[n], acc[m][n], 0, 0, 0);
                acc[m][n] = __builtin_amdgcn_mfma_f32_16x16x32_bf16(fah[m], fbl[n], acc[m][n], 0, 0, 0);
                acc[m][n] = __builtin_amdgcn_mfma_f32_16x16x32_bf16(fal[m], fbh[n], acc[m][n], 0, 0, 0);
            }
        __syncthreads();                      // reads done before next stage
    }

    // --- epilogue: per-row (max, sumexp) over this tile's valid cols.
    // C/D layout (HW-verified): col = li, row = kg*4 + reg.
    __syncthreads();
    float* pmS = (float*)lds;          // [128][2] wave-col partial max
    float* psS = (float*)lds + 256;    // [128][2] partial sumexp
    #pragma unroll
    for (int m = 0; m < 4; ++m) {
        #pragma unroll
        for (int r = 0; r < 4; ++r) {
            const int row_l = wr * 64 + m * 16 + kg * 4 + r;
            float mx = -FLT_MAX, sm = 0.f;
            float vv[4]; bool ok[4];
            #pragma unroll
            for (int n = 0; n < 4; ++n) {
                const int c = col0 + wc * 64 + n * 16 + li;
                ok[n] = (c < O);
                vv[n] = acc[m][n][r];
                if (ok[n]) mx = fmaxf(mx, vv[n]);
            }
            #pragma unroll
            for (int n = 0; n < 4; ++n)
                if (ok[n]) sm += __expf(vv[n] - mx);
            #pragma unroll
            for (int off = 1; off < 16; off <<= 1) {   // reduce 16 col-lanes
                const float mo = __shfl_xor(mx, off);
                const float so = __shfl_xor(sm, off);
                const float M2 = fmaxf(mx, mo);
                sm = sm * __expf(mx - M2) + so * __expf(mo - M2);
                mx = M2;
            }
            if (li == 0) { pmS[row_l * 2 + wc] = mx; psS[row_l * 2 + wc] = sm; }
        }
    }
    __syncthreads();
    if (t < 128) {
        const float m0 = pmS[t * 2], m1 = pmS[t * 2 + 1];
        const float s0 = psS[t * 2], s1 = psS[t * 2 + 1];
        const float M = fmaxf(m0, m1);
        const float S = s0 * __expf(m0 - M) + s1 * __expf(m1 - M);
        Pm[(size_t)(row0 + t) * T + blockIdx.x] = M;
        Ps[(size_t)(row0 + t) * T + blockIdx.x] = S;
    }
}

// ---------------------------------------------------------------------------
// gemm64: fp32 VALU projection (unchanged from R1, verified). C = X @ W^T.
// ---------------------------------------------------------------------------
__global__ __launch_bounds__(256)
void gemm64_store(const float* __restrict__ X, const float* __restrict__ W,
                  int K, int O, float* __restrict__ C)
{
    __shared__ float Xs[16][68];
    __shared__ float Wt[16][68];
    const int t = threadIdx.x, tx = t & 15, ty = t >> 4;
    const int row0 = blockIdx.y * 64, col0 = blockIdx.x * 64;

    float acc[4][4] = {};
    const int lr = t >> 2;
    const int lk = (t & 3) * 4;
    const float* Xp = X + (size_t)(row0 + lr) * K + lk;
    const float* Wp = W + (size_t)(col0 + lr) * K + lk;

    for (int k0 = 0; k0 < K; k0 += 16) {
        const float4 xv = *(const float4*)(Xp + k0);
        const float4 wv = *(const float4*)(Wp + k0);
        __syncthreads();
        Xs[lk+0][lr] = xv.x; Xs[lk+1][lr] = xv.y; Xs[lk+2][lr] = xv.z; Xs[lk+3][lr] = xv.w;
        Wt[lk+0][lr] = wv.x; Wt[lk+1][lr] = wv.y; Wt[lk+2][lr] = wv.z; Wt[lk+3][lr] = wv.w;
        __syncthreads();
#pragma unroll
        for (int kk = 0; kk < 16; ++kk) {
            const float4 a = *(const float4*)&Xs[kk][ty * 4];
            const float4 b = *(const float4*)&Wt[kk][tx * 4];
            const float av[4] = {a.x, a.y, a.z, a.w};
            const float bv[4] = {b.x, b.y, b.z, b.w};
#pragma unroll
            for (int i = 0; i < 4; ++i)
#pragma unroll
                for (int j = 0; j < 4; ++j)
                    acc[i][j] = fmaf(av[i], bv[j], acc[i][j]);
        }
    }
#pragma unroll
    for (int i = 0; i < 4; ++i) {
        const float4 v = make_float4(acc[i][0], acc[i][1], acc[i][2], acc[i][3]);
        *(float4*)(C + (size_t)(row0 + ty * 4 + i) * O + col0 + tx * 4) = v;
    }
}

// ---------------------------------------------------------------------------
// finalize (unchanged from R1, verified)
// ---------------------------------------------------------------------------
__device__ inline float block_sum(float v, float* sm)
{
#pragma unroll
    for (int off = 32; off > 0; off >>= 1) v += __shfl_xor(v, off);
    __syncthreads();
    if ((threadIdx.x & 63) == 0) sm[threadIdx.x >> 6] = v;
    __syncthreads();
    return sm[0] + sm[1] + sm[2] + sm[3];
}

__device__ inline void block_lse(float& m, float& s, float* smm, float* sms)
{
#pragma unroll
    for (int off = 32; off > 0; off >>= 1) {
        const float mo = __shfl_xor(m, off);
        const float so = __shfl_xor(s, off);
        const float M2 = fmaxf(m, mo);
        s = s * __expf(m - M2) + so * __expf(mo - M2);
        m = M2;
    }
    __syncthreads();
    if ((threadIdx.x & 63) == 0) { smm[threadIdx.x >> 6] = m; sms[threadIdx.x >> 6] = s; }
    __syncthreads();
    const float M2 = fmaxf(fmaxf(smm[0], smm[1]), fmaxf(smm[2], smm[3]));
    const float S  = sms[0] * __expf(smm[0] - M2) + sms[1] * __expf(smm[1] - M2)
                   + sms[2] * __expf(smm[2] - M2) + sms[3] * __expf(smm[3] - M2);
    m = M2; s = S;
}

__device__ inline void local_lse(const float* __restrict__ Pm,
                                 const float* __restrict__ Ps,
                                 int T, float& m, float& s)
{
    m = -FLT_MAX; s = 0.f;
    for (int i = threadIdx.x; i < T; i += 256) {
        const float mi = Pm[i], si = Ps[i];
        const float M2 = fmaxf(m, mi);
        s = s * __expf(m - M2) + si * __expf(mi - M2);
        m = M2;
    }
}

__global__ __launch_bounds__(256)
void finalize(const float* __restrict__ inp, const int* __restrict__ tgt,
              const float* __restrict__ head_w,
              const float* __restrict__ t0_w2, const float* __restrict__ t1_w2,
              const float* __restrict__ t0h, const float* __restrict__ t1h,
              const float* __restrict__ hPm, const float* __restrict__ hPs, int hT,
              const float* __restrict__ p0m, const float* __restrict__ p0s, int T0,
              const float* __restrict__ p1m, const float* __restrict__ p1s, int T1,
              float* __restrict__ out)
{
    __shared__ float sm[4], ss[4];
    const int row = blockIdx.x, t = threadIdx.x;
    const int tg = tgt[row];
    const bool in1 = (tg >= CUT0) && (tg < CUT1);
    const bool in2 = (tg >= CUT1);
    const int g = (tg < CUT0) ? tg : (in1 ? CUT0 : CUT0 + 1);

    float d;
    {
        const float4 a = *(const float4*)(inp + (size_t)row * K_IN + t * 4);
        const float4 b = *(const float4*)(head_w + (size_t)g * K_IN + t * 4);
        d = a.x * b.x + a.y * b.y + a.z * b.z + a.w * b.w;
    }
    const float dot_h = block_sum(d, sm);

    int r0 = tg - CUT0; r0 = r0 < 0 ? 0 : (r0 > T0_O - 1 ? T0_O - 1 : r0);
    d = 0.f;
    if (t < 128) {
        const float4 a = *(const float4*)(t0h + (size_t)row * H0 + t * 4);
        const float4 b = *(const float4*)(t0_w2 + (size_t)r0 * H0 + t * 4);
        d = a.x * b.x + a.y * b.y + a.z * b.z + a.w * b.w;
    }
    const float dot0 = block_sum(d, sm);

    int r1 = tg - CUT1; r1 = r1 < 0 ? 0 : (r1 > T1_O - 1 ? T1_O - 1 : r1);
    d = 0.f;
    if (t < 64) {
        const float4 a = *(const float4*)(t1h + (size_t)row * H1 + t * 4);
        const float4 b = *(const float4*)(t1_w2 + (size_t)r1 * H1 + t * 4);
        d = a.x * b.x + a.y * b.y + a.z * b.z + a.w * b.w;
    }
    const float dot1 = block_sum(d, sm);

    float m, s;
    local_lse(hPm + (size_t)row * hT, hPs + (size_t)row * hT, hT, m, s);
    block_lse(m, s, sm, ss);
    const float lse_h = m + logf(s);

    local_lse(p0m + (size_t)row * T0, p0s + (size_t)row * T0, T0, m, s);
    block_lse(m, s, sm, ss);
    const float lse_0 = m + logf(s);

    local_lse(p1m + (size_t)row * T1, p1s + (size_t)row * T1, T1, m, s);
    block_lse(m, s, sm, ss);
    const float lse_1 = m + logf(s);

    if (t == 0) {
        float res = dot_h - lse_h;
        if (in1) res += dot0 - lse_0;
        if (in2) res += dot1 - lse_1;
        out[row] = -res;
    }
}

// ---------------------------------------------------------------------------
extern "C" void kernel_launch(void* const* d_in, const int* in_sizes, int n_in,
                              void* d_out, int out_size, void* d_ws, size_t ws_size,
                              hipStream_t stream)
{
    const float* inp    = (const float*)d_in[0];
    const int*   tgt    = (const int*)  d_in[1];
    const float* head_w = (const float*)d_in[2];
    const float* t0_w1  = (const float*)d_in[3];
    const float* t0_w2  = (const float*)d_in[4];
    const float* t1_w1  = (const float*)d_in[5];
    const float* t1_w2  = (const float*)d_in[6];
    float* out = (float*)d_out;

    const int hT  = 32;    // ceil(4002/128)
    const int T0t = 125;   // 16000/128
    const int T1t = 237;   // ceil(30257/128)

    // ws carve-up (aligned 256B); total ~108 MB
    char* p = (char*)d_ws;
    #define ALLOC(name, type, count) \
        type* name = (type*)p; p += (((size_t)(count) * sizeof(type)) + 255) & ~(size_t)255;
    ALLOC(t0h,  float, (size_t)N_ROWS * H0)
    ALLOC(t1h,  float, (size_t)N_ROWS * H1)
    ALLOC(hPm,  float, (size_t)N_ROWS * hT)
    ALLOC(hPs,  float, (size_t)N_ROWS * hT)
    ALLOC(p0m,  float, (size_t)N_ROWS * T0t)
    ALLOC(p0s,  float, (size_t)N_ROWS * T0t)
    ALLOC(p1m,  float, (size_t)N_ROWS * T1t)
    ALLOC(p1s,  float, (size_t)N_ROWS * T1t)
    ALLOC(ih,   unsigned short, (size_t)N_ROWS * K_IN)
    ALLOC(il,   unsigned short, (size_t)N_ROWS * K_IN)
    ALLOC(hwh,  unsigned short, (size_t)HEAD_O * K_IN)
    ALLOC(hwl,  unsigned short, (size_t)HEAD_O * K_IN)
    ALLOC(w20h, unsigned short, (size_t)T0_O * H0)
    ALLOC(w20l, unsigned short, (size_t)T0_O * H0)
    ALLOC(w21h, unsigned short, (size_t)T1_O * H1)
    ALLOC(w21l, unsigned short, (size_t)T1_O * H1)
    ALLOC(t0hh, unsigned short, (size_t)N_ROWS * H0)
    ALLOC(t0hl, unsigned short, (size_t)N_ROWS * H0)
    ALLOC(t1hh, unsigned short, (size_t)N_ROWS * H1)
    ALLOC(t1hl, unsigned short, (size_t)N_ROWS * H1)
    #undef ALLOC

    const dim3 blk(256);
    // splits of static inputs
    split_bf16<<<dim3(1024), blk, 0, stream>>>(inp,    ih,   il,   N_ROWS * K_IN / 4);
    split_bf16<<<dim3(2048), blk, 0, stream>>>(head_w, hwh,  hwl,  HEAD_O * K_IN / 4);
    split_bf16<<<dim3(2048), blk, 0, stream>>>(t0_w2,  w20h, w20l, T0_O * H0 / 4);
    split_bf16<<<dim3(2048), blk, 0, stream>>>(t1_w2,  w21h, w21l, T1_O * H1 / 4);
    // hidden projections (fp32) + their splits
    gemm64_store<<<dim3(H0 / 64, N_ROWS / 64), blk, 0, stream>>>(inp, t0_w1, K_IN, H0, t0h);
    gemm64_store<<<dim3(H1 / 64, N_ROWS / 64), blk, 0, stream>>>(inp, t1_w1, K_IN, H1, t1h);
    split_bf16<<<dim3(512), blk, 0, stream>>>(t0h, t0hh, t0hl, N_ROWS * H0 / 4);
    split_bf16<<<dim3(256), blk, 0, stream>>>(t1h, t1hh, t1hl, N_ROWS * H1 / 4);
    // fused MFMA GEMM + online-LSE partials
    lse_mfma<<<dim3(hT,  16), blk, 0, stream>>>(ih,   il,   hwh,  hwl,  K_IN, HEAD_O, hT,  hPm, hPs);
    lse_mfma<<<dim3(T0t, 16), blk, 0, stream>>>(t0hh, t0hl, w20h, w20l, H0,   T0_O,  T0t, p0m, p0s);
    lse_mfma<<<dim3(T1t, 16), blk, 0, stream>>>(t1hh, t1hl, w21h, w21l, H1,   T1_O,  T1t, p1m, p1s);
    // per-row assembly
    finalize<<<dim3(N_ROWS), blk, 0, stream>>>(inp, tgt, head_w, t0_w2, t1_w2, t0h, t1h,
                                               hPm, hPs, hT, p0m, p0s, T0t, p1m, p1s, T1t, out);
}

// Round 3
// 496.831 us; speedup vs baseline: 2.4285x; 1.1547x over previous
//
#include <hip/hip_runtime.h>
#include <cfloat>
#include <cmath>

// Adaptive log-softmax w/ loss, forward NLL. N=2048 rows.
// R3: (a) 2-phase single-barrier pipeline (stage next tile overlapped with
// MFMA on current), (b) panel-pinned 1-D block swizzle (16 row-blocks of one
// B-panel temporally adjacent -> L2 reuse), (c) projections on the MFMA path
// too (epilogue emits fp32 + bf16 hi/lo planes; kills fp32 gemm64 + 2 splits).
// Split-precision 3-term bf16 MFMA: a*b ~= ah*bh + ah*bl + al*bh.

#define N_ROWS 2048
#define K_IN   1024
#define HEAD_O 4002
#define CUT0   4000
#define CUT1   20000
#define T0_O   16000
#define T1_O   30257
#define H0     512
#define H1     256

typedef __attribute__((ext_vector_type(8))) __bf16 bf16x8;
typedef __attribute__((ext_vector_type(4))) float f32x4;

// ---------------------------------------------------------------------------
__device__ inline unsigned short f2bf_rne(float f) {
    unsigned u = __builtin_bit_cast(unsigned, f);
    u += 0x7FFFu + ((u >> 16) & 1u);
    return (unsigned short)(u >> 16);
}
__device__ inline float bf2f(unsigned short b) {
    return __builtin_bit_cast(float, (unsigned)b << 16);
}

__global__ __launch_bounds__(256)
void split_bf16(const float* __restrict__ x, unsigned short* __restrict__ h,
                unsigned short* __restrict__ l, int n4)
{
    for (int i = blockIdx.x * 256 + threadIdx.x; i < n4; i += gridDim.x * 256) {
        const float4 v = ((const float4*)x)[i];
        ushort4 hv, lv;
        hv.x = f2bf_rne(v.x); lv.x = f2bf_rne(v.x - bf2f(hv.x));
        hv.y = f2bf_rne(v.y); lv.y = f2bf_rne(v.y - bf2f(hv.y));
        hv.z = f2bf_rne(v.z); lv.z = f2bf_rne(v.z - bf2f(hv.z));
        hv.w = f2bf_rne(v.w); lv.w = f2bf_rne(v.w - bf2f(hv.w));
        ((ushort4*)h)[i] = hv; ((ushort4*)l)[i] = lv;
    }
}

__device__ inline void gload_lds16(const unsigned short* g, unsigned short* l) {
    __builtin_amdgcn_global_load_lds(
        (const __attribute__((address_space(1))) void*)g,
        (__attribute__((address_space(3))) void*)l, 16, 0, 0);
}

// ---------------------------------------------------------------------------
// Panel-pinned swizzle: 128 consecutive bids = 8 panels x 16 row-tiles;
// under round-robin bid->XCD, each panel's 16 row-blocks run back-to-back on
// ONE XCD -> B tile L2-resident. Bijective incl. T%8 tail (linear).
// ---------------------------------------------------------------------------
__device__ inline void map_block(int bid, int T, int& panel, int& rowt)
{
    const int full = T & ~7;
    const int fb = full << 4;
    if (bid < fb) {
        panel = ((bid >> 7) << 3) + (bid & 7);
        rowt  = (bid >> 3) & 15;
    } else {
        const int l = bid - fb;
        panel = full + (l >> 4);
        rowt  = l & 15;
    }
}

// ---------------------------------------------------------------------------
// mm_mfma: D = X[M,K] @ W[O,K]^T, 128x128 tile, 4 waves (64x64 quadrant,
// 4x4 fragments), mfma_f32_16x16x32_bf16 x3 (split precision), 2-phase
// double-buffered LDS (64 KB), one barrier per K-step.
//   LSE=true : fused per-row online-LSE partials -> Pm/Ps.
//   LSE=false: store C fp32 + bf16 hi/lo planes (hidden projections).
// LDS layout per 32KB buffer: Ah|Al|Bh|Bl planes of [128 rows][32 k] bf16,
// 16B k-slots XOR-swizzled (slot = kg ^ ((row>>1)&3)) via pre-swizzled
// GLOBAL source addresses (global_load_lds writes linearly).
// ---------------------------------------------------------------------------
template<bool LSE>
__global__ __launch_bounds__(256)
void mm_mfma(const unsigned short* __restrict__ Ah, const unsigned short* __restrict__ Al,
             const unsigned short* __restrict__ Bh, const unsigned short* __restrict__ Bl,
             int K, int O, int T,
             float* __restrict__ Pm, float* __restrict__ Ps,
             float* __restrict__ C, unsigned short* __restrict__ Ch,
             unsigned short* __restrict__ Cl)
{
    __shared__ unsigned short lds[32768];   // 2 x 32 KB buffers
    const int t = threadIdx.x;
    const int lane = t & 63, w = t >> 6;
    int bx, by; map_block(blockIdx.x, T, bx, by);
    const int row0 = by * 128, col0 = bx * 128;
    const int kg = lane >> 4, li = lane & 15;
    const int wr = w >> 1, wc = w & 1;

    // staging plan: 8 issues/wave (4 planes x 2 row-groups of 16)
    const unsigned short* gsrc[8];
    unsigned short* ldst[8];
    {
        const int slot = lane & 3;
        #pragma unroll
        for (int p = 0; p < 4; ++p) {
            #pragma unroll
            for (int j2 = 0; j2 < 2; ++j2) {
                const int j = 2 * w + j2;
                const int rl = j * 16 + (lane >> 2);
                const int kd = (slot ^ ((rl >> 1) & 3)) * 8;
                const unsigned short* base;
                int grow;
                if (p < 2) { grow = row0 + rl; base = (p == 0) ? Ah : Al; }
                else       { grow = col0 + rl; if (grow > O - 1) grow = O - 1;
                             base = (p == 2) ? Bh : Bl; }
                gsrc[p * 2 + j2] = base + (size_t)grow * K + kd;
                ldst[p * 2 + j2] = lds + p * 4096 + j * 512;   // wave-uniform
            }
        }
    }

    // fragment byte-offsets within a buffer
    int aoff[4], boff[4];
    #pragma unroll
    for (int m = 0; m < 4; ++m) {
        const int ar = wr * 64 + m * 16 + li;
        aoff[m] = ar * 64 + (kg ^ ((ar >> 1) & 3)) * 16;
        const int bc = wc * 64 + m * 16 + li;
        boff[m] = 16384 + bc * 64 + (kg ^ ((bc >> 1) & 3)) * 16;
    }

    f32x4 acc[4][4];
    #pragma unroll
    for (int m = 0; m < 4; ++m)
        #pragma unroll
        for (int n = 0; n < 4; ++n) acc[m][n] = (f32x4){0.f, 0.f, 0.f, 0.f};

    const char* ldsc = (const char*)lds;
    const int nsteps = K >> 5;

    // prologue: stage buf0
    #pragma unroll
    for (int i = 0; i < 8; ++i) gload_lds16(gsrc[i], ldst[i]);
    __syncthreads();

    for (int ks = 0; ks < nsteps; ++ks) {
        const int cur = ks & 1;
        if (ks + 1 < nsteps) {           // issue next tile BEFORE compute
            const int nxt_off = (cur ^ 1) << 14;   // shorts
            const int kof = (ks + 1) << 5;
            #pragma unroll
            for (int i = 0; i < 8; ++i) gload_lds16(gsrc[i] + kof, ldst[i] + nxt_off);
        }
        const char* bufc = ldsc + (cur << 15);     // bytes
        bf16x8 fah[4], fal[4], fbh[4], fbl[4];
        #pragma unroll
        for (int m = 0; m < 4; ++m) {
            fah[m] = *(const bf16x8*)(bufc + aoff[m]);
            fal[m] = *(const bf16x8*)(bufc + aoff[m] + 8192);
            fbh[m] = *(const bf16x8*)(bufc + boff[m]);
            fbl[m] = *(const bf16x8*)(bufc + boff[m] + 8192);
        }
        #pragma unroll
        for (int m = 0; m < 4; ++m)
            #pragma unroll
            for (int n = 0; n < 4; ++n) {
                acc[m][n] = __builtin_amdgcn_mfma_f32_16x16x32_bf16(fah[m], fbh[n], acc[m][n], 0, 0, 0);
                acc[m][n] = __builtin_amdgcn_mfma_f32_16x16x32_bf16(fah[m], fbl[n], acc[m][n], 0, 0, 0);
                acc[m][n] = __builtin_amdgcn_mfma_f32_16x16x32_bf16(fal[m], fbh[n], acc[m][n], 0, 0, 0);
            }
        __syncthreads();   // drains next-stage vmcnt + this step's ds reads
    }

    if (LSE) {
        // per-row (max, sumexp) over this tile's valid cols.
        // C/D layout (HW-verified): col = li, row = kg*4 + reg.
        float* pmS = (float*)lds;
        float* psS = (float*)lds + 256;
        #pragma unroll
        for (int m = 0; m < 4; ++m) {
            #pragma unroll
            for (int r = 0; r < 4; ++r) {
                const int row_l = wr * 64 + m * 16 + kg * 4 + r;
                float mx = -FLT_MAX, sm = 0.f;
                float vv[4]; bool ok[4];
                #pragma unroll
                for (int n = 0; n < 4; ++n) {
                    const int c = col0 + wc * 64 + n * 16 + li;
                    ok[n] = (c < O);
                    vv[n] = acc[m][n][r];
                    if (ok[n]) mx = fmaxf(mx, vv[n]);
                }
                #pragma unroll
                for (int n = 0; n < 4; ++n)
                    if (ok[n]) sm += __expf(vv[n] - mx);
                #pragma unroll
                for (int off = 1; off < 16; off <<= 1) {
                    const float mo = __shfl_xor(mx, off);
                    const float so = __shfl_xor(sm, off);
                    const float M2 = fmaxf(mx, mo);
                    sm = sm * __expf(mx - M2) + so * __expf(mo - M2);
                    mx = M2;
                }
                if (li == 0) { pmS[row_l * 2 + wc] = mx; psS[row_l * 2 + wc] = sm; }
            }
        }
        __syncthreads();
        if (t < 128) {
            const float m0 = pmS[t * 2], m1 = pmS[t * 2 + 1];
            const float s0 = psS[t * 2], s1 = psS[t * 2 + 1];
            const float M = fmaxf(m0, m1);
            const float S = s0 * __expf(m0 - M) + s1 * __expf(m1 - M);
            Pm[(size_t)(row0 + t) * T + bx] = M;
            Ps[(size_t)(row0 + t) * T + bx] = S;
        }
    } else {
        // projection epilogue: fp32 C + bf16 hi/lo planes (O % 128 == 0)
        #pragma unroll
        for (int m = 0; m < 4; ++m)
            #pragma unroll
            for (int n = 0; n < 4; ++n)
                #pragma unroll
                for (int r = 0; r < 4; ++r) {
                    const int row = row0 + wr * 64 + m * 16 + kg * 4 + r;
                    const int col = col0 + wc * 64 + n * 16 + li;
                    const float v = acc[m][n][r];
                    const size_t idx = (size_t)row * O + col;
                    C[idx] = v;
                    const unsigned short h = f2bf_rne(v);
                    Ch[idx] = h;
                    Cl[idx] = f2bf_rne(v - bf2f(h));
                }
    }
}

// ---------------------------------------------------------------------------
// finalize (unchanged, verified)
// ---------------------------------------------------------------------------
__device__ inline float block_sum(float v, float* sm)
{
#pragma unroll
    for (int off = 32; off > 0; off >>= 1) v += __shfl_xor(v, off);
    __syncthreads();
    if ((threadIdx.x & 63) == 0) sm[threadIdx.x >> 6] = v;
    __syncthreads();
    return sm[0] + sm[1] + sm[2] + sm[3];
}

__device__ inline void block_lse(float& m, float& s, float* smm, float* sms)
{
#pragma unroll
    for (int off = 32; off > 0; off >>= 1) {
        const float mo = __shfl_xor(m, off);
        const float so = __shfl_xor(s, off);
        const float M2 = fmaxf(m, mo);
        s = s * __expf(m - M2) + so * __expf(mo - M2);
        m = M2;
    }
    __syncthreads();
    if ((threadIdx.x & 63) == 0) { smm[threadIdx.x >> 6] = m; sms[threadIdx.x >> 6] = s; }
    __syncthreads();
    const float M2 = fmaxf(fmaxf(smm[0], smm[1]), fmaxf(smm[2], smm[3]));
    const float S  = sms[0] * __expf(smm[0] - M2) + sms[1] * __expf(smm[1] - M2)
                   + sms[2] * __expf(smm[2] - M2) + sms[3] * __expf(smm[3] - M2);
    m = M2; s = S;
}

__device__ inline void local_lse(const float* __restrict__ Pm,
                                 const float* __restrict__ Ps,
                                 int T, float& m, float& s)
{
    m = -FLT_MAX; s = 0.f;
    for (int i = threadIdx.x; i < T; i += 256) {
        const float mi = Pm[i], si = Ps[i];
        const float M2 = fmaxf(m, mi);
        s = s * __expf(m - M2) + si * __expf(mi - M2);
        m = M2;
    }
}

__global__ __launch_bounds__(256)
void finalize(const float* __restrict__ inp, const int* __restrict__ tgt,
              const float* __restrict__ head_w,
              const float* __restrict__ t0_w2, const float* __restrict__ t1_w2,
              const float* __restrict__ t0h, const float* __restrict__ t1h,
              const float* __restrict__ hPm, const float* __restrict__ hPs, int hT,
              const float* __restrict__ p0m, const float* __restrict__ p0s, int T0,
              const float* __restrict__ p1m, const float* __restrict__ p1s, int T1,
              float* __restrict__ out)
{
    __shared__ float sm[4], ss[4];
    const int row = blockIdx.x, t = threadIdx.x;
    const int tg = tgt[row];
    const bool in1 = (tg >= CUT0) && (tg < CUT1);
    const bool in2 = (tg >= CUT1);
    const int g = (tg < CUT0) ? tg : (in1 ? CUT0 : CUT0 + 1);

    float d;
    {
        const float4 a = *(const float4*)(inp + (size_t)row * K_IN + t * 4);
        const float4 b = *(const float4*)(head_w + (size_t)g * K_IN + t * 4);
        d = a.x * b.x + a.y * b.y + a.z * b.z + a.w * b.w;
    }
    const float dot_h = block_sum(d, sm);

    int r0 = tg - CUT0; r0 = r0 < 0 ? 0 : (r0 > T0_O - 1 ? T0_O - 1 : r0);
    d = 0.f;
    if (t < 128) {
        const float4 a = *(const float4*)(t0h + (size_t)row * H0 + t * 4);
        const float4 b = *(const float4*)(t0_w2 + (size_t)r0 * H0 + t * 4);
        d = a.x * b.x + a.y * b.y + a.z * b.z + a.w * b.w;
    }
    const float dot0 = block_sum(d, sm);

    int r1 = tg - CUT1; r1 = r1 < 0 ? 0 : (r1 > T1_O - 1 ? T1_O - 1 : r1);
    d = 0.f;
    if (t < 64) {
        const float4 a = *(const float4*)(t1h + (size_t)row * H1 + t * 4);
        const float4 b = *(const float4*)(t1_w2 + (size_t)r1 * H1 + t * 4);
        d = a.x * b.x + a.y * b.y + a.z * b.z + a.w * b.w;
    }
    const float dot1 = block_sum(d, sm);

    float m, s;
    local_lse(hPm + (size_t)row * hT, hPs + (size_t)row * hT, hT, m, s);
    block_lse(m, s, sm, ss);
    const float lse_h = m + logf(s);

    local_lse(p0m + (size_t)row * T0, p0s + (size_t)row * T0, T0, m, s);
    block_lse(m, s, sm, ss);
    const float lse_0 = m + logf(s);

    local_lse(p1m + (size_t)row * T1, p1s + (size_t)row * T1, T1, m, s);
    block_lse(m, s, sm, ss);
    const float lse_1 = m + logf(s);

    if (t == 0) {
        float res = dot_h - lse_h;
        if (in1) res += dot0 - lse_0;
        if (in2) res += dot1 - lse_1;
        out[row] = -res;
    }
}

// ---------------------------------------------------------------------------
extern "C" void kernel_launch(void* const* d_in, const int* in_sizes, int n_in,
                              void* d_out, int out_size, void* d_ws, size_t ws_size,
                              hipStream_t stream)
{
    const float* inp    = (const float*)d_in[0];
    const int*   tgt    = (const int*)  d_in[1];
    const float* head_w = (const float*)d_in[2];
    const float* t0_w1  = (const float*)d_in[3];
    const float* t0_w2  = (const float*)d_in[4];
    const float* t1_w1  = (const float*)d_in[5];
    const float* t1_w2  = (const float*)d_in[6];
    float* out = (float*)d_out;

    const int hT  = 32;    // ceil(4002/128)
    const int T0t = 125;   // 16000/128
    const int T1t = 237;   // ceil(30257/128)

    char* p = (char*)d_ws;
    #define ALLOC(name, type, count) \
        type* name = (type*)p; p += (((size_t)(count) * sizeof(type)) + 255) & ~(size_t)255;
    ALLOC(t0h,  float, (size_t)N_ROWS * H0)
    ALLOC(t1h,  float, (size_t)N_ROWS * H1)
    ALLOC(hPm,  float, (size_t)N_ROWS * hT)
    ALLOC(hPs,  float, (size_t)N_ROWS * hT)
    ALLOC(p0m,  float, (size_t)N_ROWS * T0t)
    ALLOC(p0s,  float, (size_t)N_ROWS * T0t)
    ALLOC(p1m,  float, (size_t)N_ROWS * T1t)
    ALLOC(p1s,  float, (size_t)N_ROWS * T1t)
    ALLOC(ih,   unsigned short, (size_t)N_ROWS * K_IN)
    ALLOC(il,   unsigned short, (size_t)N_ROWS * K_IN)
    ALLOC(hwh,  unsigned short, (size_t)HEAD_O * K_IN)
    ALLOC(hwl,  unsigned short, (size_t)HEAD_O * K_IN)
    ALLOC(w10h, unsigned short, (size_t)H0 * K_IN)
    ALLOC(w10l, unsigned short, (size_t)H0 * K_IN)
    ALLOC(w11h, unsigned short, (size_t)H1 * K_IN)
    ALLOC(w11l, unsigned short, (size_t)H1 * K_IN)
    ALLOC(w20h, unsigned short, (size_t)T0_O * H0)
    ALLOC(w20l, unsigned short, (size_t)T0_O * H0)
    ALLOC(w21h, unsigned short, (size_t)T1_O * H1)
    ALLOC(w21l, unsigned short, (size_t)T1_O * H1)
    ALLOC(t0hh, unsigned short, (size_t)N_ROWS * H0)
    ALLOC(t0hl, unsigned short, (size_t)N_ROWS * H0)
    ALLOC(t1hh, unsigned short, (size_t)N_ROWS * H1)
    ALLOC(t1hl, unsigned short, (size_t)N_ROWS * H1)
    #undef ALLOC

    const dim3 blk(256);
    // input/weight splits
    split_bf16<<<dim3(1024), blk, 0, stream>>>(inp,    ih,   il,   N_ROWS * K_IN / 4);
    split_bf16<<<dim3(2048), blk, 0, stream>>>(head_w, hwh,  hwl,  HEAD_O * K_IN / 4);
    split_bf16<<<dim3(512),  blk, 0, stream>>>(t0_w1,  w10h, w10l, H0 * K_IN / 4);
    split_bf16<<<dim3(256),  blk, 0, stream>>>(t1_w1,  w11h, w11l, H1 * K_IN / 4);
    split_bf16<<<dim3(2048), blk, 0, stream>>>(t0_w2,  w20h, w20l, T0_O * H0 / 4);
    split_bf16<<<dim3(2048), blk, 0, stream>>>(t1_w2,  w21h, w21l, T1_O * H1 / 4);

    // head LSE (independent of projections -> first)
    mm_mfma<true><<<dim3(hT * 16), blk, 0, stream>>>(
        ih, il, hwh, hwl, K_IN, HEAD_O, hT, hPm, hPs, nullptr, nullptr, nullptr);

    // hidden projections on MFMA (emit fp32 + hi/lo planes)
    mm_mfma<false><<<dim3((H0 / 128) * 16), blk, 0, stream>>>(
        ih, il, w10h, w10l, K_IN, H0, H0 / 128, nullptr, nullptr, t0h, t0hh, t0hl);
    mm_mfma<false><<<dim3((H1 / 128) * 16), blk, 0, stream>>>(
        ih, il, w11h, w11l, K_IN, H1, H1 / 128, nullptr, nullptr, t1h, t1hh, t1hl);

    // tail LSE GEMMs
    mm_mfma<true><<<dim3(T0t * 16), blk, 0, stream>>>(
        t0hh, t0hl, w20h, w20l, H0, T0_O, T0t, p0m, p0s, nullptr, nullptr, nullptr);
    mm_mfma<true><<<dim3(T1t * 16), blk, 0, stream>>>(
        t1hh, t1hl, w21h, w21l, H1, T1_O, T1t, p1m, p1s, nullptr, nullptr, nullptr);

    // per-row assembly
    finalize<<<dim3(N_ROWS), blk, 0, stream>>>(inp, tgt, head_w, t0_w2, t1_w2, t0h, t1h,
                                               hPm, hPs, hT, p0m, p0s, T0t, p1m, p1s, T1t, out);
}

// Round 4
// 437.268 us; speedup vs baseline: 2.7592x; 1.1362x over previous
//
#include <hip/hip_runtime.h>
#include <cfloat>
#include <cmath>

// Adaptive log-softmax w/ loss, forward NLL. N=2048 rows.
// R4: (a) row compaction for tail clusters (only masked-in rows GEMM'd;
// ~-39% MFMA FLOPs), (b) counted s_waitcnt vmcnt(8) pipeline (prefetch loads
// stay in flight across barriers; no vmcnt(0) drain in main loop) + setprio,
// (c) all fp32->bf16 hi/lo splits fused into one launch.
// Split-precision 3-term bf16 MFMA: a*b ~= ah*bh + ah*bl + al*bh.

#define N_ROWS 2048
#define K_IN   1024
#define HEAD_O 4002
#define CUT0   4000
#define CUT1   20000
#define T0_O   16000
#define T1_O   30257
#define H0     512
#define H1     256

typedef __attribute__((ext_vector_type(8))) __bf16 bf16x8;
typedef __attribute__((ext_vector_type(4))) float f32x4;

// ---------------------------------------------------------------------------
__device__ inline unsigned short f2bf_rne(float f) {
    unsigned u = __builtin_bit_cast(unsigned, f);
    u += 0x7FFFu + ((u >> 16) & 1u);
    return (unsigned short)(u >> 16);
}
__device__ inline float bf2f(unsigned short b) {
    return __builtin_bit_cast(float, (unsigned)b << 16);
}

__device__ inline void gload_lds16(const unsigned short* g, unsigned short* l) {
    __builtin_amdgcn_global_load_lds(
        (const __attribute__((address_space(1))) void*)g,
        (__attribute__((address_space(3))) void*)l, 16, 0, 0);
}

// ---------------------------------------------------------------------------
// Fused hi/lo split of all six fp32 operands (one launch, memory-bound).
// ---------------------------------------------------------------------------
__global__ __launch_bounds__(256)
void split_all(const float* __restrict__ s0, const float* __restrict__ s1,
               const float* __restrict__ s2, const float* __restrict__ s3,
               const float* __restrict__ s4, const float* __restrict__ s5,
               unsigned short* __restrict__ h0, unsigned short* __restrict__ l0,
               unsigned short* __restrict__ h1, unsigned short* __restrict__ l1,
               unsigned short* __restrict__ h2, unsigned short* __restrict__ l2,
               unsigned short* __restrict__ h3, unsigned short* __restrict__ l3,
               unsigned short* __restrict__ h4, unsigned short* __restrict__ l4,
               unsigned short* __restrict__ h5, unsigned short* __restrict__ l5)
{
    constexpr int e0 = (N_ROWS * K_IN) / 4;            // inp
    constexpr int e1 = e0 + (HEAD_O * K_IN) / 4;       // head_w
    constexpr int e2 = e1 + (H0 * K_IN) / 4;           // t0_w1
    constexpr int e3 = e2 + (H1 * K_IN) / 4;           // t1_w1
    constexpr int e4 = e3 + (T0_O * H0) / 4;           // t0_w2
    constexpr int e5 = e4 + (T1_O * H1) / 4;           // t1_w2
    for (int i = blockIdx.x * 256 + threadIdx.x; i < e5; i += gridDim.x * 256) {
        const float* src; unsigned short* h; unsigned short* l; int off;
        if      (i < e0) { src = s0; h = h0; l = l0; off = i; }
        else if (i < e1) { src = s1; h = h1; l = l1; off = i - e0; }
        else if (i < e2) { src = s2; h = h2; l = l2; off = i - e1; }
        else if (i < e3) { src = s3; h = h3; l = l3; off = i - e2; }
        else if (i < e4) { src = s4; h = h4; l = l4; off = i - e3; }
        else             { src = s5; h = h5; l = l5; off = i - e4; }
        const float4 v = ((const float4*)src)[off];
        ushort4 hv, lv;
        hv.x = f2bf_rne(v.x); lv.x = f2bf_rne(v.x - bf2f(hv.x));
        hv.y = f2bf_rne(v.y); lv.y = f2bf_rne(v.y - bf2f(hv.y));
        hv.z = f2bf_rne(v.z); lv.z = f2bf_rne(v.z - bf2f(hv.z));
        hv.w = f2bf_rne(v.w); lv.w = f2bf_rne(v.w - bf2f(hv.w));
        ((ushort4*)h)[off] = hv; ((ushort4*)l)[off] = lv;
    }
}

// ---------------------------------------------------------------------------
// Row compaction: slot assignment per cluster (order irrelevant; the
// rowOf/cidx bijection makes outputs permutation-invariant).
// ---------------------------------------------------------------------------
__global__ __launch_bounds__(256)
void compact(const int* __restrict__ tgt, int* __restrict__ cnt,
             int* __restrict__ rowOf0, int* __restrict__ cidx0,
             int* __restrict__ rowOf1, int* __restrict__ cidx1)
{
    const int row = blockIdx.x * 256 + threadIdx.x;
    if (row >= N_ROWS) return;
    const int tg = tgt[row];
    if (tg >= CUT0 && tg < CUT1) {
        const int s = atomicAdd(&cnt[0], 1);
        rowOf0[s] = row; cidx0[row] = s;
    } else if (tg >= CUT1) {
        const int s = atomicAdd(&cnt[1], 1);
        rowOf1[s] = row; cidx1[row] = s;
    }
}

// ---------------------------------------------------------------------------
// Panel-pinned swizzle (verified R3: FETCH 254->28 MB).
// ---------------------------------------------------------------------------
__device__ inline void map_block(int bid, int T, int& panel, int& rowt)
{
    const int full = T & ~7;
    const int fb = full << 4;
    if (bid < fb) {
        panel = ((bid >> 7) << 3) + (bid & 7);
        rowt  = (bid >> 3) & 15;
    } else {
        const int l = bid - fb;
        panel = full + (l >> 4);
        rowt  = l & 15;
    }
}

// ---------------------------------------------------------------------------
// mm_mfma: D = X[M,K] @ W[O,K]^T, 128x128 tile, 4 waves (64x64 quadrant,
// 4x4 fragments), mfma_f32_16x16x32_bf16 x3 (split precision).
// 2-deep LDS double-buffer with COUNTED vmcnt(8): prefetch loads stay in
// flight across barriers; no vmcnt(0) drain in the main loop (T4).
//   cnt    : live-row count; blocks with row0 >= *cnt exit (nullptr = all).
//   rowIdx : A-row gather indices (compaction; nullptr = identity).
//   LSE=true : fused per-row online-LSE partials -> Pm/Ps.
//   LSE=false: store C fp32 + bf16 hi/lo planes (hidden projections).
// ---------------------------------------------------------------------------
template<bool LSE>
__global__ __launch_bounds__(256)
void mm_mfma(const unsigned short* __restrict__ Ah, const unsigned short* __restrict__ Al,
             const unsigned short* __restrict__ Bh, const unsigned short* __restrict__ Bl,
             int K, int O, int T,
             const int* __restrict__ cnt, const int* __restrict__ rowIdx,
             float* __restrict__ Pm, float* __restrict__ Ps,
             float* __restrict__ C, unsigned short* __restrict__ Ch,
             unsigned short* __restrict__ Cl)
{
    __shared__ unsigned short lds[32768];   // 2 x 32 KB buffers
    const int t = threadIdx.x;
    const int lane = t & 63, w = t >> 6;
    int bx, by; map_block(blockIdx.x, T, bx, by);
    const int row0 = by * 128, col0 = bx * 128;
    if (cnt && row0 >= *cnt) return;        // dead block (uniform) -> exit
    const int kg = lane >> 4, li = lane & 15;
    const int wr = w >> 1, wc = w & 1;

    // staging plan: 8 issues/wave (4 planes x 2 row-groups of 16)
    const unsigned short* gsrc[8];
    unsigned short* ldst[8];
    {
        const int slot = lane & 3;
        #pragma unroll
        for (int p = 0; p < 4; ++p) {
            #pragma unroll
            for (int j2 = 0; j2 < 2; ++j2) {
                const int j = 2 * w + j2;
                const int rl = j * 16 + (lane >> 2);
                const int kd = (slot ^ ((rl >> 1) & 3)) * 8;
                const unsigned short* base;
                int grow;
                if (p < 2) {
                    grow = row0 + rl;
                    if (rowIdx) grow = rowIdx[grow] & (N_ROWS - 1);  // sanitized gather
                    base = (p == 0) ? Ah : Al;
                } else {
                    grow = col0 + rl; if (grow > O - 1) grow = O - 1;
                    base = (p == 2) ? Bh : Bl;
                }
                gsrc[p * 2 + j2] = base + (size_t)grow * K + kd;
                ldst[p * 2 + j2] = lds + p * 4096 + j * 512;   // wave-uniform
            }
        }
    }

    // fragment byte-offsets within a buffer
    int aoff[4], boff[4];
    #pragma unroll
    for (int m = 0; m < 4; ++m) {
        const int ar = wr * 64 + m * 16 + li;
        aoff[m] = ar * 64 + (kg ^ ((ar >> 1) & 3)) * 16;
        const int bc = wc * 64 + m * 16 + li;
        boff[m] = 16384 + bc * 64 + (kg ^ ((bc >> 1) & 3)) * 16;
    }

    f32x4 acc[4][4];
    #pragma unroll
    for (int m = 0; m < 4; ++m)
        #pragma unroll
        for (int n = 0; n < 4; ++n) acc[m][n] = (f32x4){0.f, 0.f, 0.f, 0.f};

    const char* ldsc = (const char*)lds;
    const int nsteps = K >> 5;   // >= 8 always

    auto compute_step = [&](const char* bufc) {
        bf16x8 fah[4], fal[4], fbh[4], fbl[4];
        #pragma unroll
        for (int m = 0; m < 4; ++m) {
            fah[m] = *(const bf16x8*)(bufc + aoff[m]);
            fal[m] = *(const bf16x8*)(bufc + aoff[m] + 8192);
            fbh[m] = *(const bf16x8*)(bufc + boff[m]);
            fbl[m] = *(const bf16x8*)(bufc + boff[m] + 8192);
        }
        __builtin_amdgcn_s_setprio(1);
        #pragma unroll
        for (int m = 0; m < 4; ++m)
            #pragma unroll
            for (int n = 0; n < 4; ++n) {
                acc[m][n] = __builtin_amdgcn_mfma_f32_16x16x32_bf16(fah[m], fbh[n], acc[m][n], 0, 0, 0);
                acc[m][n] = __builtin_amdgcn_mfma_f32_16x16x32_bf16(fah[m], fbl[n], acc[m][n], 0, 0, 0);
                acc[m][n] = __builtin_amdgcn_mfma_f32_16x16x32_bf16(fal[m], fbh[n], acc[m][n], 0, 0, 0);
            }
        __builtin_amdgcn_s_setprio(0);
    };

    // prologue: stage buf0 (8 loads in flight)
    #pragma unroll
    for (int i = 0; i < 8; ++i) gload_lds16(gsrc[i], ldst[i]);

    for (int ks = 0; ks < nsteps - 1; ++ks) {
        const int cur = ks & 1;
        {   // issue next tile (vm outstanding: 16)
            const int nxt_off = (cur ^ 1) << 14;   // shorts
            const int kof = (ks + 1) << 5;
            #pragma unroll
            for (int i = 0; i < 8; ++i) gload_lds16(gsrc[i] + kof, ldst[i] + nxt_off);
        }
        asm volatile("s_waitcnt vmcnt(8)" ::: "memory");  // cur's loads landed
        __builtin_amdgcn_s_barrier();                     // ... in every wave
        compute_step(ldsc + (cur << 15));
        asm volatile("" ::: "memory");                    // pin reads above bar
        __builtin_amdgcn_s_barrier();                     // reads done before overwrite
    }
    // peeled last step: drain fully
    asm volatile("s_waitcnt vmcnt(0)" ::: "memory");
    __builtin_amdgcn_s_barrier();
    compute_step(ldsc + (((nsteps - 1) & 1) << 15));
    asm volatile("" ::: "memory");
    __builtin_amdgcn_s_barrier();                         // before LDS reuse below

    if (LSE) {
        // per-row (max, sumexp) over this tile's valid cols.
        // C/D layout (HW-verified): col = li, row = kg*4 + reg.
        float* pmS = (float*)lds;
        float* psS = (float*)lds + 256;
        #pragma unroll
        for (int m = 0; m < 4; ++m) {
            #pragma unroll
            for (int r = 0; r < 4; ++r) {
                const int row_l = wr * 64 + m * 16 + kg * 4 + r;
                float mx = -FLT_MAX, sm = 0.f;
                float vv[4]; bool ok[4];
                #pragma unroll
                for (int n = 0; n < 4; ++n) {
                    const int c = col0 + wc * 64 + n * 16 + li;
                    ok[n] = (c < O);
                    vv[n] = acc[m][n][r];
                    if (ok[n]) mx = fmaxf(mx, vv[n]);
                }
                #pragma unroll
                for (int n = 0; n < 4; ++n)
                    if (ok[n]) sm += __expf(vv[n] - mx);
                #pragma unroll
                for (int off = 1; off < 16; off <<= 1) {
                    const float mo = __shfl_xor(mx, off);
                    const float so = __shfl_xor(sm, off);
                    const float M2 = fmaxf(mx, mo);
                    sm = sm * __expf(mx - M2) + so * __expf(mo - M2);
                    mx = M2;
                }
                if (li == 0) { pmS[row_l * 2 + wc] = mx; psS[row_l * 2 + wc] = sm; }
            }
        }
        __syncthreads();
        if (t < 128) {
            const float m0 = pmS[t * 2], m1 = pmS[t * 2 + 1];
            const float s0 = psS[t * 2], s1 = psS[t * 2 + 1];
            const float M = fmaxf(m0, m1);
            const float S = s0 * __expf(m0 - M) + s1 * __expf(m1 - M);
            Pm[(size_t)(row0 + t) * T + bx] = M;
            Ps[(size_t)(row0 + t) * T + bx] = S;
        }
    } else {
        // projection epilogue: fp32 C + bf16 hi/lo planes (O % 128 == 0)
        #pragma unroll
        for (int m = 0; m < 4; ++m)
            #pragma unroll
            for (int n = 0; n < 4; ++n)
                #pragma unroll
                for (int r = 0; r < 4; ++r) {
                    const int row = row0 + wr * 64 + m * 16 + kg * 4 + r;
                    const int col = col0 + wc * 64 + n * 16 + li;
                    const float v = acc[m][n][r];
                    const size_t idx = (size_t)row * O + col;
                    C[idx] = v;
                    const unsigned short h = f2bf_rne(v);
                    Ch[idx] = h;
                    Cl[idx] = f2bf_rne(v - bf2f(h));
                }
    }
}

// ---------------------------------------------------------------------------
// finalize: combine LSE partials + recompute gathered target logits.
// Tail data is at COMPACTED slots (cidx0/cidx1).
// ---------------------------------------------------------------------------
__device__ inline float block_sum(float v, float* sm)
{
#pragma unroll
    for (int off = 32; off > 0; off >>= 1) v += __shfl_xor(v, off);
    __syncthreads();
    if ((threadIdx.x & 63) == 0) sm[threadIdx.x >> 6] = v;
    __syncthreads();
    return sm[0] + sm[1] + sm[2] + sm[3];
}

__device__ inline void block_lse(float& m, float& s, float* smm, float* sms)
{
#pragma unroll
    for (int off = 32; off > 0; off >>= 1) {
        const float mo = __shfl_xor(m, off);
        const float so = __shfl_xor(s, off);
        const float M2 = fmaxf(m, mo);
        s = s * __expf(m - M2) + so * __expf(mo - M2);
        m = M2;
    }
    __syncthreads();
    if ((threadIdx.x & 63) == 0) { smm[threadIdx.x >> 6] = m; sms[threadIdx.x >> 6] = s; }
    __syncthreads();
    const float M2 = fmaxf(fmaxf(smm[0], smm[1]), fmaxf(smm[2], smm[3]));
    const float S  = sms[0] * __expf(smm[0] - M2) + sms[1] * __expf(smm[1] - M2)
                   + sms[2] * __expf(smm[2] - M2) + sms[3] * __expf(smm[3] - M2);
    m = M2; s = S;
}

__device__ inline void local_lse(const float* __restrict__ Pm,
                                 const float* __restrict__ Ps,
                                 int T, float& m, float& s)
{
    m = -FLT_MAX; s = 0.f;
    for (int i = threadIdx.x; i < T; i += 256) {
        const float mi = Pm[i], si = Ps[i];
        const float M2 = fmaxf(m, mi);
        s = s * __expf(m - M2) + si * __expf(mi - M2);
        m = M2;
    }
}

__global__ __launch_bounds__(256)
void finalize(const float* __restrict__ inp, const int* __restrict__ tgt,
              const float* __restrict__ head_w,
              const int* __restrict__ cidx0, const int* __restrict__ cidx1,
              const float* __restrict__ t0h, const float* __restrict__ t1h,
              const float* __restrict__ hPm, const float* __restrict__ hPs, int hT,
              const float* __restrict__ p0m, const float* __restrict__ p0s, int T0,
              const float* __restrict__ p1m, const float* __restrict__ p1s, int T1,
              const float* __restrict__ t0_w2, const float* __restrict__ t1_w2,
              float* __restrict__ out)
{
    __shared__ float sm[4], ss[4];
    const int row = blockIdx.x, t = threadIdx.x;
    const int tg = tgt[row];
    const bool in1 = (tg >= CUT0) && (tg < CUT1);
    const bool in2 = (tg >= CUT1);
    const int g = (tg < CUT0) ? tg : (in1 ? CUT0 : CUT0 + 1);
    const int c0 = in1 ? cidx0[row] : 0;   // sanitized (slot 0 exists or unused)
    const int c1 = in2 ? cidx1[row] : 0;

    float d;
    {
        const float4 a = *(const float4*)(inp + (size_t)row * K_IN + t * 4);
        const float4 b = *(const float4*)(head_w + (size_t)g * K_IN + t * 4);
        d = a.x * b.x + a.y * b.y + a.z * b.z + a.w * b.w;
    }
    const float dot_h = block_sum(d, sm);

    int r0 = tg - CUT0; r0 = r0 < 0 ? 0 : (r0 > T0_O - 1 ? T0_O - 1 : r0);
    d = 0.f;
    if (t < 128) {
        const float4 a = *(const float4*)(t0h + (size_t)c0 * H0 + t * 4);
        const float4 b = *(const float4*)(t0_w2 + (size_t)r0 * H0 + t * 4);
        d = a.x * b.x + a.y * b.y + a.z * b.z + a.w * b.w;
    }
    const float dot0 = block_sum(d, sm);

    int r1 = tg - CUT1; r1 = r1 < 0 ? 0 : (r1 > T1_O - 1 ? T1_O - 1 : r1);
    d = 0.f;
    if (t < 64) {
        const float4 a = *(const float4*)(t1h + (size_t)c1 * H1 + t * 4);
        const float4 b = *(const float4*)(t1_w2 + (size_t)r1 * H1 + t * 4);
        d = a.x * b.x + a.y * b.y + a.z * b.z + a.w * b.w;
    }
    const float dot1 = block_sum(d, sm);

    float m, s;
    local_lse(hPm + (size_t)row * hT, hPs + (size_t)row * hT, hT, m, s);
    block_lse(m, s, sm, ss);
    const float lse_h = m + logf(s);

    local_lse(p0m + (size_t)c0 * T0, p0s + (size_t)c0 * T0, T0, m, s);
    block_lse(m, s, sm, ss);
    const float lse_0 = m + logf(s);

    local_lse(p1m + (size_t)c1 * T1, p1s + (size_t)c1 * T1, T1, m, s);
    block_lse(m, s, sm, ss);
    const float lse_1 = m + logf(s);

    if (t == 0) {
        float res = dot_h - lse_h;
        if (in1) res += dot0 - lse_0;
        if (in2) res += dot1 - lse_1;
        out[row] = -res;
    }
}

// ---------------------------------------------------------------------------
extern "C" void kernel_launch(void* const* d_in, const int* in_sizes, int n_in,
                              void* d_out, int out_size, void* d_ws, size_t ws_size,
                              hipStream_t stream)
{
    const float* inp    = (const float*)d_in[0];
    const int*   tgt    = (const int*)  d_in[1];
    const float* head_w = (const float*)d_in[2];
    const float* t0_w1  = (const float*)d_in[3];
    const float* t0_w2  = (const float*)d_in[4];
    const float* t1_w1  = (const float*)d_in[5];
    const float* t1_w2  = (const float*)d_in[6];
    float* out = (float*)d_out;

    const int hT  = 32;    // ceil(4002/128)
    const int T0t = 125;   // 16000/128
    const int T1t = 237;   // ceil(30257/128)

    char* p = (char*)d_ws;
    #define ALLOC(name, type, count) \
        type* name = (type*)p; p += (((size_t)(count) * sizeof(type)) + 255) & ~(size_t)255;
    ALLOC(t0h,  float, (size_t)N_ROWS * H0)
    ALLOC(t1h,  float, (size_t)N_ROWS * H1)
    ALLOC(hPm,  float, (size_t)N_ROWS * hT)
    ALLOC(hPs,  float, (size_t)N_ROWS * hT)
    ALLOC(p0m,  float, (size_t)N_ROWS * T0t)
    ALLOC(p0s,  float, (size_t)N_ROWS * T0t)
    ALLOC(p1m,  float, (size_t)N_ROWS * T1t)
    ALLOC(p1s,  float, (size_t)N_ROWS * T1t)
    ALLOC(ih,   unsigned short, (size_t)N_ROWS * K_IN)
    ALLOC(il,   unsigned short, (size_t)N_ROWS * K_IN)
    ALLOC(hwh,  unsigned short, (size_t)HEAD_O * K_IN)
    ALLOC(hwl,  unsigned short, (size_t)HEAD_O * K_IN)
    ALLOC(w10h, unsigned short, (size_t)H0 * K_IN)
    ALLOC(w10l, unsigned short, (size_t)H0 * K_IN)
    ALLOC(w11h, unsigned short, (size_t)H1 * K_IN)
    ALLOC(w11l, unsigned short, (size_t)H1 * K_IN)
    ALLOC(w20h, unsigned short, (size_t)T0_O * H0)
    ALLOC(w20l, unsigned short, (size_t)T0_O * H0)
    ALLOC(w21h, unsigned short, (size_t)T1_O * H1)
    ALLOC(w21l, unsigned short, (size_t)T1_O * H1)
    ALLOC(t0hh, unsigned short, (size_t)N_ROWS * H0)
    ALLOC(t0hl, unsigned short, (size_t)N_ROWS * H0)
    ALLOC(t1hh, unsigned short, (size_t)N_ROWS * H1)
    ALLOC(t1hl, unsigned short, (size_t)N_ROWS * H1)
    ALLOC(cnt,    int, 2)
    ALLOC(rowOf0, int, N_ROWS)
    ALLOC(cidx0,  int, N_ROWS)
    ALLOC(rowOf1, int, N_ROWS)
    ALLOC(cidx1,  int, N_ROWS)
    #undef ALLOC

    const dim3 blk(256);

    hipMemsetAsync(cnt, 0, 2 * sizeof(int), stream);
    compact<<<dim3(N_ROWS / 256), blk, 0, stream>>>(tgt, cnt, rowOf0, cidx0, rowOf1, cidx1);

    split_all<<<dim3(2048), blk, 0, stream>>>(
        inp, head_w, t0_w1, t1_w1, t0_w2, t1_w2,
        ih, il, hwh, hwl, w10h, w10l, w11h, w11l, w20h, w20l, w21h, w21l);

    // head LSE: all rows
    mm_mfma<true><<<dim3(hT * 16), blk, 0, stream>>>(
        ih, il, hwh, hwl, K_IN, HEAD_O, hT, nullptr, nullptr,
        hPm, hPs, nullptr, nullptr, nullptr);

    // hidden projections on compacted rows (gathered A) -> fp32 + hi/lo planes
    mm_mfma<false><<<dim3((H0 / 128) * 16), blk, 0, stream>>>(
        ih, il, w10h, w10l, K_IN, H0, H0 / 128, cnt + 0, rowOf0,
        nullptr, nullptr, t0h, t0hh, t0hl);
    mm_mfma<false><<<dim3((H1 / 128) * 16), blk, 0, stream>>>(
        ih, il, w11h, w11l, K_IN, H1, H1 / 128, cnt + 1, rowOf1,
        nullptr, nullptr, t1h, t1hh, t1hl);

    // tail LSE GEMMs on compacted rows
    mm_mfma<true><<<dim3(T0t * 16), blk, 0, stream>>>(
        t0hh, t0hl, w20h, w20l, H0, T0_O, T0t, cnt + 0, nullptr,
        p0m, p0s, nullptr, nullptr, nullptr);
    mm_mfma<true><<<dim3(T1t * 16), blk, 0, stream>>>(
        t1hh, t1hl, w21h, w21l, H1, T1_O, T1t, cnt + 1, nullptr,
        p1m, p1s, nullptr, nullptr, nullptr);

    // per-row assembly
    finalize<<<dim3(N_ROWS), blk, 0, stream>>>(
        inp, tgt, head_w, cidx0, cidx1, t0h, t1h,
        hPm, hPs, hT, p0m, p0s, T0t, p1m, p1s, T1t, t0_w2, t1_w2, out);
}